// Round 1
// baseline (16783.553 us; speedup 1.0000x reference)
//
#include <hip/hip_runtime.h>

#define LN_EPS 1e-3f
#define G3 6144

typedef short s8v __attribute__((ext_vector_type(8)));
typedef float f4v __attribute__((ext_vector_type(4)));
typedef unsigned short u16;

__device__ __forceinline__ u16 f2bf(float f) {
  unsigned int x = __float_as_uint(f);
  x += 0x7fffu + ((x >> 16) & 1u);
  return (u16)(x >> 16);
}
__device__ __forceinline__ float bf2f(u16 u) {
  return __uint_as_float(((unsigned int)u) << 16);
}

// ---------------- fp32 -> bf16 conversion ----------------
__global__ void k_cvt(const float* __restrict__ src, u16* __restrict__ dst, int n) {
  int i = blockIdx.x * blockDim.x + threadIdx.x;
  int stride = gridDim.x * blockDim.x;
  for (; i < n; i += stride) dst[i] = f2bf(src[i]);
}

__global__ void k_hinit(const float* __restrict__ h0, float* __restrict__ hf,
                        u16* __restrict__ hb) {
  int i = blockIdx.x * 256 + threadIdx.x;
  float v = h0[i];
  hf[i] = v;
  hb[i] = f2bf(v);
}

// ---------------- generic bf16 MFMA GEMM ----------------
// C[M,N] = A[M,K] @ Bw[N,K]^T (+bias[col]) (+extra bf16[row*ldc+col])
// BM=64, BN=128, BK=64. 256 threads = 4 waves (2x2), wave tile 32x64.
template <bool AF32, bool OUTBF16>
__global__ __launch_bounds__(256) void k_gemm(
    const void* __restrict__ Av, int lda, int K, const u16* __restrict__ Bw,
    float* __restrict__ Cf, u16* __restrict__ Cb, int ldc,
    const float* __restrict__ bias, const u16* __restrict__ extra) {
  const int tid = threadIdx.x;
  const int m0 = blockIdx.x * 64;
  const int n0 = blockIdx.y * 128;
  __shared__ __align__(16) u16 As[64][72];
  __shared__ __align__(16) u16 Bs[128][72];
  const int lane = tid & 63;
  const int w = tid >> 6;
  const int wr = w >> 1;   // 0..1
  const int wc = w & 1;    // 0..1
  const int lr = lane & 15;
  const int lk = lane >> 4;  // 0..3

  f4v acc[2][4];
#pragma unroll
  for (int m = 0; m < 2; ++m)
#pragma unroll
    for (int n = 0; n < 4; ++n) acc[m][n] = (f4v)(0.0f);

  const int nstage = K >> 6;
  for (int s = 0; s < nstage; ++s) {
    const int k0 = s << 6;
    // stage A tile (64 x 64)
#pragma unroll
    for (int it = 0; it < 2; ++it) {
      int c = tid + it * 256;
      int row = c >> 3, k8 = (c & 7) << 3;
      if (AF32) {
        const float* ap = (const float*)Av + (size_t)(m0 + row) * lda + k0 + k8;
        float4 f0 = *(const float4*)ap;
        float4 f1 = *(const float4*)(ap + 4);
        s8v v;
        v[0] = (short)f2bf(f0.x); v[1] = (short)f2bf(f0.y);
        v[2] = (short)f2bf(f0.z); v[3] = (short)f2bf(f0.w);
        v[4] = (short)f2bf(f1.x); v[5] = (short)f2bf(f1.y);
        v[6] = (short)f2bf(f1.z); v[7] = (short)f2bf(f1.w);
        *(s8v*)&As[row][k8] = v;
      } else {
        *(s8v*)&As[row][k8] =
            *(const s8v*)((const u16*)Av + (size_t)(m0 + row) * lda + k0 + k8);
      }
    }
    // stage B tile (128 x 64) from [N,K] bf16 weights
#pragma unroll
    for (int it = 0; it < 4; ++it) {
      int c = tid + it * 256;
      int row = c >> 3, k8 = (c & 7) << 3;
      *(s8v*)&Bs[row][k8] = *(const s8v*)(Bw + (size_t)(n0 + row) * K + k0 + k8);
    }
    __syncthreads();
#pragma unroll
    for (int kk = 0; kk < 2; ++kk) {
      const int koff = kk * 32 + lk * 8;
      s8v a[2], b[4];
#pragma unroll
      for (int m = 0; m < 2; ++m)
        a[m] = *(const s8v*)&As[wr * 32 + m * 16 + lr][koff];
#pragma unroll
      for (int n = 0; n < 4; ++n)
        b[n] = *(const s8v*)&Bs[wc * 64 + n * 16 + lr][koff];
#pragma unroll
      for (int m = 0; m < 2; ++m)
#pragma unroll
        for (int n = 0; n < 4; ++n)
          acc[m][n] =
              __builtin_amdgcn_mfma_f32_16x16x32_bf16(a[m], b[n], acc[m][n], 0, 0, 0);
    }
    __syncthreads();
  }
  // epilogue: C/D layout col=lane&15, row=(lane>>4)*4+reg  [m89-verified]
#pragma unroll
  for (int m = 0; m < 2; ++m) {
#pragma unroll
    for (int n = 0; n < 4; ++n) {
#pragma unroll
      for (int r = 0; r < 4; ++r) {
        int row = m0 + wr * 32 + m * 16 + lk * 4 + r;
        int col = n0 + wc * 64 + n * 16 + lr;
        float v = acc[m][n][r];
        if (bias) v += bias[col];
        if (extra) v += bf2f(extra[(size_t)row * ldc + col]);
        if (OUTBF16)
          Cb[(size_t)row * ldc + col] = f2bf(v);
        else
          Cf[(size_t)row * ldc + col] = v;
      }
    }
  }
}

// ---------------- za = elu(LN(concat(z@zw^T+zb, a@aw^T))) ----------------
__global__ __launch_bounds__(256) void k_za(
    const float* __restrict__ zsrc, const float* __restrict__ act,
    const float* __restrict__ zw, const float* __restrict__ zb,
    const float* __restrict__ aw, const float* __restrict__ lns,
    const float* __restrict__ lnb, u16* __restrict__ za) {
  const int b = blockIdx.x, tid = threadIdx.x;
  __shared__ float zsh[64];
  __shared__ float ash[16];
  __shared__ float red[256];
  if (tid < 64) zsh[tid] = zsrc[b * 64 + tid];
  if (tid < 10) ash[tid] = act[b * 10 + tid];
  __syncthreads();
  float x[4];
#pragma unroll
  for (int i = 0; i < 2; ++i) {
    int c = tid + i * 256;  // cols 0..511: z part
    const float* wp = zw + c * 64;
    float a = zb[c];
#pragma unroll
    for (int k = 0; k < 64; ++k) a += zsh[k] * wp[k];
    x[i] = a;
  }
#pragma unroll
  for (int i = 2; i < 4; ++i) {
    int c2 = tid + (i - 2) * 256;  // cols 512..1023: action part (no bias)
    const float* wp = aw + c2 * 10;
    float a = 0.f;
#pragma unroll
    for (int k = 0; k < 10; ++k) a += ash[k] * wp[k];
    x[i] = a;
  }
  float s = x[0] + x[1] + x[2] + x[3];
  red[tid] = s;
  __syncthreads();
  for (int o = 128; o > 0; o >>= 1) {
    if (tid < o) red[tid] += red[tid + o];
    __syncthreads();
  }
  float mu = red[0] * (1.0f / 1024.0f);
  __syncthreads();
  float q = 0.f;
#pragma unroll
  for (int i = 0; i < 4; ++i) {
    float d = x[i] - mu;
    q += d * d;
  }
  red[tid] = q;
  __syncthreads();
  for (int o = 128; o > 0; o >>= 1) {
    if (tid < o) red[tid] += red[tid + o];
    __syncthreads();
  }
  float rs = rsqrtf(red[0] * (1.0f / 1024.0f) + LN_EPS);
#pragma unroll
  for (int i = 0; i < 4; ++i) {
    int c = tid + i * 256;
    float y = (x[i] - mu) * rs * lns[c] + lnb[c];
    y = y > 0.f ? y : expm1f(y);
    za[b * 1024 + c] = f2bf(y);
  }
}

// ---------------- GRU gates ----------------
__global__ __launch_bounds__(256) void k_gate(
    const float* __restrict__ gi, const float* __restrict__ gh,
    const float* __restrict__ bih, const float* __restrict__ bhh,
    float* __restrict__ hf, u16* __restrict__ hb, float* __restrict__ feat,
    int t) {
  int idx = blockIdx.x * 256 + threadIdx.x;  // 524288 elems
  int b = idx >> 11, j = idx & 2047;
  size_t rb = (size_t)b * G3;
  float vr = gi[rb + j] + bih[j] + gh[rb + j] + bhh[j];
  float vu = gi[rb + 2048 + j] + bih[2048 + j] + gh[rb + 2048 + j] + bhh[2048 + j];
  float ic = gi[rb + 4096 + j] + bih[4096 + j];
  float hc = gh[rb + 4096 + j] + bhh[4096 + j];
  float r = 1.f / (1.f + expf(-vr));
  float u = 1.f / (1.f + expf(-vu));
  float c = tanhf(ic + r * hc);
  float h1 = (1.f - u) * c + u * hf[idx];
  hf[idx] = h1;
  hb[idx] = f2bf(h1);
  feat[(size_t)(t * 256 + b) * 2112 + j] = h1;
}

// ---------------- LN + ELU (rows of 1024) ----------------
template <bool SRCBF16>
__global__ __launch_bounds__(256) void k_lnelu(const void* __restrict__ xsrc,
                                               const float* __restrict__ s,
                                               const float* __restrict__ bb,
                                               u16* __restrict__ out) {
  int row = blockIdx.x, tid = threadIdx.x;
  __shared__ float red[256];
  float v[4];
#pragma unroll
  for (int i = 0; i < 4; ++i) {
    size_t idx = (size_t)row * 1024 + tid + i * 256;
    v[i] = SRCBF16 ? bf2f(((const u16*)xsrc)[idx]) : ((const float*)xsrc)[idx];
  }
  float sm = v[0] + v[1] + v[2] + v[3];
  red[tid] = sm;
  __syncthreads();
  for (int o = 128; o > 0; o >>= 1) {
    if (tid < o) red[tid] += red[tid + o];
    __syncthreads();
  }
  float mu = red[0] * (1.0f / 1024.0f);
  __syncthreads();
  float q = 0.f;
#pragma unroll
  for (int i = 0; i < 4; ++i) {
    float d = v[i] - mu;
    q += d * d;
  }
  red[tid] = q;
  __syncthreads();
  for (int o = 128; o > 0; o >>= 1) {
    if (tid < o) red[tid] += red[tid + o];
    __syncthreads();
  }
  float rs = rsqrtf(red[0] * (1.0f / 1024.0f) + LN_EPS);
#pragma unroll
  for (int i = 0; i < 4; ++i) {
    int c = tid + i * 256;
    float y = (v[i] - mu) * rs * s[c] + bb[c];
    y = y > 0.f ? y : expm1f(y);
    out[(size_t)row * 1024 + c] = f2bf(y);
  }
}

// ---------------- z sample ----------------
__global__ void k_z1(const float* __restrict__ posts_t,
                     const float* __restrict__ noise_t, float* __restrict__ zout,
                     float* __restrict__ feat, int t) {
  int idx = blockIdx.x * 256 + threadIdx.x;  // 16384 elems
  int b = idx >> 6, j = idx & 63;
  float mean = posts_t[b * 128 + j];
  float sraw = posts_t[b * 128 + 64 + j];
  float sd = 2.f / (1.f + expf(-sraw)) + 0.1f;
  float z = mean + sd * noise_t[b * 64 + j];
  zout[b * 64 + j] = z;
  feat[(size_t)(t * 256 + b) * 2112 + 2048 + j] = z;
}

extern "C" void kernel_launch(void* const* d_in, const int* in_sizes, int n_in,
                              void* d_out, int out_size, void* d_ws,
                              size_t ws_size, hipStream_t stream) {
  const float* embeds = (const float*)d_in[0];
  const float* actions = (const float*)d_in[1];
  const float* h_t = (const float*)d_in[2];
  const float* z_t = (const float*)d_in[3];
  const float* noise = (const float*)d_in[4];
  const float* z_mlp_w = (const float*)d_in[5];
  const float* z_mlp_b = (const float*)d_in[6];
  const float* a_mlp_w = (const float*)d_in[7];
  const float* ln_za_s = (const float*)d_in[8];
  const float* ln_za_b = (const float*)d_in[9];
  const float* gru_wih = (const float*)d_in[10];
  const float* gru_whh = (const float*)d_in[11];
  const float* gru_bih = (const float*)d_in[12];
  const float* gru_bhh = (const float*)d_in[13];
  const float* post_h_w = (const float*)d_in[14];
  const float* post_h_b = (const float*)d_in[15];
  const float* post_e_w = (const float*)d_in[16];
  const float* post_e_b = (const float*)d_in[17];
  const float* ln_post_s = (const float*)d_in[18];
  const float* ln_post_b = (const float*)d_in[19];
  const float* post_w = (const float*)d_in[20];
  const float* post_b = (const float*)d_in[21];
  const float* prior_h_w = (const float*)d_in[22];
  const float* prior_h_b = (const float*)d_in[23];
  const float* ln_prior_s = (const float*)d_in[24];
  const float* ln_prior_b = (const float*)d_in[25];
  const float* prior_w = (const float*)d_in[26];
  const float* prior_b = (const float*)d_in[27];

  float* out = (float*)d_out;
  float* out_priors = out;                 // [64,256,128]
  float* out_posts = out + 2097152;        // [64,256,128]
  float* out_z = out + 4194304;            // [64,256,64]
  float* out_feat = out + 5242880;         // [64,256,2112]

  char* ws = (char*)d_ws;
  size_t off = 0;
  auto alloc = [&](size_t bytes) {
    char* p = ws + off;
    off += (bytes + 255) & ~(size_t)255;
    return p;
  };
  u16* wih_b = (u16*)alloc((size_t)6144 * 1024 * 2);
  u16* whh_b = (u16*)alloc((size_t)6144 * 2048 * 2);
  u16* posth_b = (u16*)alloc((size_t)1024 * 2048 * 2);
  u16* priorh_b = (u16*)alloc((size_t)1024 * 2048 * 2);
  u16* postw_b = (u16*)alloc((size_t)128 * 1024 * 2);
  u16* priorw_b = (u16*)alloc((size_t)128 * 1024 * 2);
  u16* poste_b = (u16*)alloc((size_t)1024 * 1536 * 2);
  u16* za_b = (u16*)alloc((size_t)256 * 1024 * 2);
  u16* hb = (u16*)alloc((size_t)256 * 2048 * 2);
  float* hf = (float*)alloc((size_t)256 * 2048 * 4);
  float* xbuf = (float*)alloc((size_t)256 * 1024 * 4);
  u16* p_b = (u16*)alloc((size_t)256 * 1024 * 2);
  char* uni = alloc(67108864);
  // scan phase: e_part at uni+0 (33.55MB), gi at +33554432, gh at +39845888
  u16* e_part = (u16*)uni;
  float* gi = (float*)(uni + 33554432);
  float* gh = (float*)(uni + 39845888);
  // prior phase (after scan; overwrites dead scan buffers):
  u16* prx_b = (u16*)uni;                   // [16384,1024] bf16 pre-LN
  u16* p_pr = (u16*)(uni + 33554432);       // [16384,1024] bf16 post-LN/ELU

  // ---- weight conversions + h init ----
  k_cvt<<<512, 256, 0, stream>>>(gru_wih, wih_b, 6144 * 1024);
  k_cvt<<<512, 256, 0, stream>>>(gru_whh, whh_b, 6144 * 2048);
  k_cvt<<<512, 256, 0, stream>>>(post_h_w, posth_b, 1024 * 2048);
  k_cvt<<<512, 256, 0, stream>>>(prior_h_w, priorh_b, 1024 * 2048);
  k_cvt<<<64, 256, 0, stream>>>(post_w, postw_b, 128 * 1024);
  k_cvt<<<64, 256, 0, stream>>>(prior_w, priorw_b, 128 * 1024);
  k_cvt<<<512, 256, 0, stream>>>(post_e_w, poste_b, 1024 * 1536);
  k_hinit<<<2048, 256, 0, stream>>>(h_t, hf, hb);

  // ---- batched embed projection: e_part = embeds@post_e_w^T + post_e_b ----
  k_gemm<true, true><<<dim3(256, 8), 256, 0, stream>>>(
      embeds, 1536, 1536, poste_b, nullptr, e_part, 1024, post_e_b, nullptr);

  // ---- sequential scan ----
  for (int t = 0; t < 64; ++t) {
    const float* zsrc = (t == 0) ? z_t : (out_z + (size_t)(t - 1) * 16384);
    k_za<<<256, 256, 0, stream>>>(zsrc, actions + (size_t)t * 2560, z_mlp_w,
                                  z_mlp_b, a_mlp_w, ln_za_s, ln_za_b, za_b);
    k_gemm<false, false><<<dim3(4, 48), 256, 0, stream>>>(
        za_b, 1024, 1024, wih_b, gi, nullptr, G3, nullptr, nullptr);
    k_gemm<false, false><<<dim3(4, 48), 256, 0, stream>>>(
        hb, 2048, 2048, whh_b, gh, nullptr, G3, nullptr, nullptr);
    k_gate<<<2048, 256, 0, stream>>>(gi, gh, gru_bih, gru_bhh, hf, hb, out_feat, t);
    k_gemm<false, false><<<dim3(4, 8), 256, 0, stream>>>(
        hb, 2048, 2048, posth_b, xbuf, nullptr, 1024, post_h_b,
        e_part + (size_t)t * 262144);
    k_lnelu<false><<<256, 256, 0, stream>>>(xbuf, ln_post_s, ln_post_b, p_b);
    k_gemm<false, false><<<dim3(4, 1), 256, 0, stream>>>(
        p_b, 1024, 1024, postw_b, out_posts + (size_t)t * 32768, nullptr, 128,
        post_b, nullptr);
    k_z1<<<64, 256, 0, stream>>>(out_posts + (size_t)t * 32768,
                                 noise + (size_t)t * 16384,
                                 out_z + (size_t)t * 16384, out_feat, t);
  }

  // ---- batched prior head ----
  k_gemm<true, true><<<dim3(256, 8), 256, 0, stream>>>(
      out_feat, 2112, 2048, priorh_b, nullptr, prx_b, 1024, prior_h_b, nullptr);
  k_lnelu<true><<<16384, 256, 0, stream>>>(prx_b, ln_prior_s, ln_prior_b, p_pr);
  k_gemm<false, false><<<dim3(256, 1), 256, 0, stream>>>(
      p_pr, 1024, 1024, priorw_b, out_priors, nullptr, 128, prior_b, nullptr);
}

// Round 2
// 8536.729 us; speedup vs baseline: 1.9660x; 1.9660x over previous
//
#include <hip/hip_runtime.h>

#define LN_EPS 1e-3f

typedef short s8v __attribute__((ext_vector_type(8)));
typedef short s4v __attribute__((ext_vector_type(4)));
typedef float f4v __attribute__((ext_vector_type(4)));
typedef unsigned short u16;

__device__ __forceinline__ u16 f2bf(float f) {
  unsigned int x = __float_as_uint(f);
  x += 0x7fffu + ((x >> 16) & 1u);
  return (u16)(x >> 16);
}
__device__ __forceinline__ float bf2f(u16 u) {
  return __uint_as_float(((unsigned int)u) << 16);
}

// ---------------- fp32 -> bf16 conversion ----------------
__global__ void k_cvt(const float* __restrict__ src, u16* __restrict__ dst, int n) {
  int i = blockIdx.x * blockDim.x + threadIdx.x;
  int stride = gridDim.x * blockDim.x;
  for (; i < n; i += stride) dst[i] = f2bf(src[i]);
}

// pack Wpack[8192,3072]: rows 0-2047 [wih_r|whh_r], 2048-4095 [wih_u|whh_u],
// 4096-6143 [wih_c|0], 6144-8191 [0|whh_c]
__global__ void k_pack(const float* __restrict__ wih, const float* __restrict__ whh,
                       u16* __restrict__ wp) {
  size_t i4 = ((size_t)blockIdx.x * 256 + threadIdx.x) * 4;
  int n = (int)(i4 / 3072);
  int k = (int)(i4 % 3072);
  int g = n >> 11;      // 0:r 1:u 2:ic 3:hc
  int j = n & 2047;
  s4v v;
#pragma unroll
  for (int q = 0; q < 4; ++q) {
    int kk = k + q;
    float x = 0.f;
    if (g <= 1) {
      x = (kk < 1024) ? wih[(size_t)(g * 2048 + j) * 1024 + kk]
                      : whh[(size_t)(g * 2048 + j) * 2048 + kk - 1024];
    } else if (g == 2) {
      x = (kk < 1024) ? wih[(size_t)(4096 + j) * 1024 + kk] : 0.f;
    } else {
      x = (kk >= 1024) ? whh[(size_t)(4096 + j) * 2048 + kk - 1024] : 0.f;
    }
    v[q] = (short)f2bf(x);
  }
  *(s4v*)(wp + i4) = v;
}

// h0 -> hf (f32) and A_cat h-slot (bf16)
__global__ void k_hinit(const float* __restrict__ h0, float* __restrict__ hf,
                        u16* __restrict__ acat) {
  int i = blockIdx.x * 256 + threadIdx.x;  // 524288
  int b = i >> 11, j = i & 2047;
  float v = h0[i];
  hf[i] = v;
  acat[(size_t)b * 3072 + 1024 + j] = f2bf(v);
}

// ---------------- generic 8-wave bf16 MFMA GEMM ----------------
// C[M,N] = A[M,K] @ Bw[N,:]^T (+bias[col]) (+extra bf16[row*ldc+col])
// BM=64, BN=128, BK=64. 512 threads = 8 waves (2x4), wave tile 32x32.
// GRUKR: grid=(256), per-block K-range + chunked XCD swizzle.
template <bool AF32, bool OUTBF16, bool GRUKR>
__global__ __launch_bounds__(512) void k_gemm8(
    const void* __restrict__ Av, int lda, const u16* __restrict__ Bw, int ldb,
    int ks0, int ke0, float* __restrict__ Cf, u16* __restrict__ Cb, int ldc,
    const float* __restrict__ bias, const u16* __restrict__ extra) {
  int bx, by, ks = ks0, ke = ke0;
  if (GRUKR) {
    int hw = blockIdx.x;
    int logical = (hw & 7) * 32 + (hw >> 3);  // chunked: 32 consecutive per XCD
    bx = logical & 3;
    by = logical >> 2;
    if (by < 32) { ks = 0; ke = 48; }         // r,u: full K=3072
    else if (by < 48) { ks = 0; ke = 16; }    // ic: za part (K 0-1023)
    else { ks = 16; ke = 48; }                // hc: h part (K 1024-3071)
  } else {
    bx = blockIdx.x;
    by = blockIdx.y;
  }
  const int tid = threadIdx.x;
  const int m0 = bx * 64;
  const int n0 = by * 128;
  __shared__ __align__(16) u16 As[64][72];
  __shared__ __align__(16) u16 Bs[128][72];
  const int lane = tid & 63;
  const int w = tid >> 6;
  const int wr = w >> 2;     // 0..1
  const int wc = w & 3;      // 0..3
  const int lr = lane & 15;
  const int lk = lane >> 4;  // 0..3

  f4v acc[2][2];
#pragma unroll
  for (int m = 0; m < 2; ++m)
#pragma unroll
    for (int n = 0; n < 2; ++n) acc[m][n] = (f4v)(0.0f);

  for (int s = ks; s < ke; ++s) {
    const int k0 = s << 6;
    // stage A tile (64 x 64): 1 load/thread
    {
      int row = tid >> 3, k8 = (tid & 7) << 3;
      if (AF32) {
        const float* ap = (const float*)Av + (size_t)(m0 + row) * lda + k0 + k8;
        float4 f0 = *(const float4*)ap;
        float4 f1 = *(const float4*)(ap + 4);
        s8v v;
        v[0] = (short)f2bf(f0.x); v[1] = (short)f2bf(f0.y);
        v[2] = (short)f2bf(f0.z); v[3] = (short)f2bf(f0.w);
        v[4] = (short)f2bf(f1.x); v[5] = (short)f2bf(f1.y);
        v[6] = (short)f2bf(f1.z); v[7] = (short)f2bf(f1.w);
        *(s8v*)&As[row][k8] = v;
      } else {
        *(s8v*)&As[row][k8] =
            *(const s8v*)((const u16*)Av + (size_t)(m0 + row) * lda + k0 + k8);
      }
    }
    // stage B tile (128 x 64): 2 loads/thread
#pragma unroll
    for (int it = 0; it < 2; ++it) {
      int c = tid + it * 512;
      int row = c >> 3, k8 = (c & 7) << 3;
      *(s8v*)&Bs[row][k8] = *(const s8v*)(Bw + (size_t)(n0 + row) * ldb + k0 + k8);
    }
    __syncthreads();
#pragma unroll
    for (int kk = 0; kk < 2; ++kk) {
      const int koff = kk * 32 + lk * 8;
      s8v a[2], b[2];
      a[0] = *(const s8v*)&As[wr * 32 + lr][koff];
      a[1] = *(const s8v*)&As[wr * 32 + 16 + lr][koff];
      b[0] = *(const s8v*)&Bs[wc * 32 + lr][koff];
      b[1] = *(const s8v*)&Bs[wc * 32 + 16 + lr][koff];
#pragma unroll
      for (int m = 0; m < 2; ++m)
#pragma unroll
        for (int n = 0; n < 2; ++n)
          acc[m][n] =
              __builtin_amdgcn_mfma_f32_16x16x32_bf16(a[m], b[n], acc[m][n], 0, 0, 0);
    }
    __syncthreads();
  }
  // epilogue: C/D layout col=lane&15, row=(lane>>4)*4+reg
#pragma unroll
  for (int m = 0; m < 2; ++m) {
#pragma unroll
    for (int n = 0; n < 2; ++n) {
#pragma unroll
      for (int r = 0; r < 4; ++r) {
        int row = m0 + wr * 32 + m * 16 + lk * 4 + r;
        int col = n0 + wc * 32 + n * 16 + lr;
        float v = acc[m][n][r];
        if (bias) v += bias[col];
        if (extra) v += bf2f(extra[(size_t)row * ldc + col]);
        if (OUTBF16)
          Cb[(size_t)row * ldc + col] = f2bf(v);
        else
          Cf[(size_t)row * ldc + col] = v;
      }
    }
  }
}

// ---------------- za = elu(LN(concat(z@zw^T+zb, a@aw^T))) -> A_cat[:,0:1024] --
__global__ __launch_bounds__(256) void k_za(
    const float* __restrict__ zsrc, const float* __restrict__ act,
    const float* __restrict__ zw, const float* __restrict__ zb,
    const float* __restrict__ aw, const float* __restrict__ lns,
    const float* __restrict__ lnb, u16* __restrict__ acat) {
  const int b = blockIdx.x, tid = threadIdx.x;
  __shared__ float zsh[64];
  __shared__ float ash[16];
  __shared__ float red[256];
  if (tid < 64) zsh[tid] = zsrc[b * 64 + tid];
  if (tid < 10) ash[tid] = act[b * 10 + tid];
  __syncthreads();
  float x[4];
#pragma unroll
  for (int i = 0; i < 2; ++i) {
    int c = tid + i * 256;  // cols 0..511: z part
    const float* wp = zw + c * 64;
    float a = zb[c];
#pragma unroll
    for (int k = 0; k < 64; ++k) a += zsh[k] * wp[k];
    x[i] = a;
  }
#pragma unroll
  for (int i = 2; i < 4; ++i) {
    int c2 = tid + (i - 2) * 256;  // cols 512..1023: action part (no bias)
    const float* wp = aw + c2 * 10;
    float a = 0.f;
#pragma unroll
    for (int k = 0; k < 10; ++k) a += ash[k] * wp[k];
    x[i] = a;
  }
  float s = x[0] + x[1] + x[2] + x[3];
  red[tid] = s;
  __syncthreads();
  for (int o = 128; o > 0; o >>= 1) {
    if (tid < o) red[tid] += red[tid + o];
    __syncthreads();
  }
  float mu = red[0] * (1.0f / 1024.0f);
  __syncthreads();
  float q = 0.f;
#pragma unroll
  for (int i = 0; i < 4; ++i) {
    float d = x[i] - mu;
    q += d * d;
  }
  red[tid] = q;
  __syncthreads();
  for (int o = 128; o > 0; o >>= 1) {
    if (tid < o) red[tid] += red[tid + o];
    __syncthreads();
  }
  float rs = rsqrtf(red[0] * (1.0f / 1024.0f) + LN_EPS);
#pragma unroll
  for (int i = 0; i < 4; ++i) {
    int c = tid + i * 256;
    float y = (x[i] - mu) * rs * lns[c] + lnb[c];
    y = y > 0.f ? y : expm1f(y);
    acat[(size_t)b * 3072 + c] = f2bf(y);
  }
}

// ---------------- GRU gates ----------------
// gout[b, 0:2048]=r_pre-b, [2048:4096]=u_pre-b, [4096:6144]=ic-b, [6144:8192]=hc-b
__global__ __launch_bounds__(256) void k_gate(
    const float* __restrict__ gout, const float* __restrict__ bih,
    const float* __restrict__ bhh, float* __restrict__ hf,
    u16* __restrict__ acat, float* __restrict__ feat, int t) {
  int idx = blockIdx.x * 256 + threadIdx.x;  // 524288 elems
  int b = idx >> 11, j = idx & 2047;
  size_t rb = (size_t)b * 8192;
  float vr = gout[rb + j] + bih[j] + bhh[j];
  float vu = gout[rb + 2048 + j] + bih[2048 + j] + bhh[2048 + j];
  float ic = gout[rb + 4096 + j] + bih[4096 + j];
  float hc = gout[rb + 6144 + j] + bhh[4096 + j];
  float r = 1.f / (1.f + expf(-vr));
  float u = 1.f / (1.f + expf(-vu));
  float c = tanhf(ic + r * hc);
  float h1 = (1.f - u) * c + u * hf[idx];
  hf[idx] = h1;
  acat[(size_t)b * 3072 + 1024 + j] = f2bf(h1);
  feat[(size_t)(t * 256 + b) * 2112 + j] = h1;
}

// ---------------- LN + ELU (rows of 1024) ----------------
template <bool SRCBF16>
__global__ __launch_bounds__(256) void k_lnelu(const void* __restrict__ xsrc,
                                               const float* __restrict__ s,
                                               const float* __restrict__ bb,
                                               u16* __restrict__ out) {
  int row = blockIdx.x, tid = threadIdx.x;
  __shared__ float red[256];
  float v[4];
#pragma unroll
  for (int i = 0; i < 4; ++i) {
    size_t idx = (size_t)row * 1024 + tid + i * 256;
    v[i] = SRCBF16 ? bf2f(((const u16*)xsrc)[idx]) : ((const float*)xsrc)[idx];
  }
  float sm = v[0] + v[1] + v[2] + v[3];
  red[tid] = sm;
  __syncthreads();
  for (int o = 128; o > 0; o >>= 1) {
    if (tid < o) red[tid] += red[tid + o];
    __syncthreads();
  }
  float mu = red[0] * (1.0f / 1024.0f);
  __syncthreads();
  float q = 0.f;
#pragma unroll
  for (int i = 0; i < 4; ++i) {
    float d = v[i] - mu;
    q += d * d;
  }
  red[tid] = q;
  __syncthreads();
  for (int o = 128; o > 0; o >>= 1) {
    if (tid < o) red[tid] += red[tid + o];
    __syncthreads();
  }
  float rs = rsqrtf(red[0] * (1.0f / 1024.0f) + LN_EPS);
#pragma unroll
  for (int i = 0; i < 4; ++i) {
    int c = tid + i * 256;
    float y = (v[i] - mu) * rs * s[c] + bb[c];
    y = y > 0.f ? y : expm1f(y);
    out[(size_t)row * 1024 + c] = f2bf(y);
  }
}

// ---------------- post GEMM (M=256,N=128,K=1024) + z sample, fused ----------
__global__ __launch_bounds__(512) void k_postz(
    const u16* __restrict__ Ab, const u16* __restrict__ Bw,
    const float* __restrict__ bias, float* __restrict__ posts_t,
    const float* __restrict__ noise_t, float* __restrict__ zout,
    float* __restrict__ feat, int t) {
  const int tid = threadIdx.x;
  const int m0 = blockIdx.x * 64;
  __shared__ __align__(16) u16 As[64][72];
  __shared__ __align__(16) u16 Bs[128][72];
  __shared__ float ps[64][132];
  const int lane = tid & 63;
  const int w = tid >> 6;
  const int wr = w >> 2;
  const int wc = w & 3;
  const int lr = lane & 15;
  const int lk = lane >> 4;

  f4v acc[2][2];
#pragma unroll
  for (int m = 0; m < 2; ++m)
#pragma unroll
    for (int n = 0; n < 2; ++n) acc[m][n] = (f4v)(0.0f);

  for (int s = 0; s < 16; ++s) {
    const int k0 = s << 6;
    {
      int row = tid >> 3, k8 = (tid & 7) << 3;
      *(s8v*)&As[row][k8] =
          *(const s8v*)(Ab + (size_t)(m0 + row) * 1024 + k0 + k8);
    }
#pragma unroll
    for (int it = 0; it < 2; ++it) {
      int c = tid + it * 512;
      int row = c >> 3, k8 = (c & 7) << 3;
      *(s8v*)&Bs[row][k8] = *(const s8v*)(Bw + (size_t)row * 1024 + k0 + k8);
    }
    __syncthreads();
#pragma unroll
    for (int kk = 0; kk < 2; ++kk) {
      const int koff = kk * 32 + lk * 8;
      s8v a[2], b[2];
      a[0] = *(const s8v*)&As[wr * 32 + lr][koff];
      a[1] = *(const s8v*)&As[wr * 32 + 16 + lr][koff];
      b[0] = *(const s8v*)&Bs[wc * 32 + lr][koff];
      b[1] = *(const s8v*)&Bs[wc * 32 + 16 + lr][koff];
#pragma unroll
      for (int m = 0; m < 2; ++m)
#pragma unroll
        for (int n = 0; n < 2; ++n)
          acc[m][n] =
              __builtin_amdgcn_mfma_f32_16x16x32_bf16(a[m], b[n], acc[m][n], 0, 0, 0);
    }
    __syncthreads();
  }
#pragma unroll
  for (int m = 0; m < 2; ++m) {
#pragma unroll
    for (int n = 0; n < 2; ++n) {
#pragma unroll
      for (int r = 0; r < 4; ++r) {
        int lrow = wr * 32 + m * 16 + lk * 4 + r;
        int col = wc * 32 + n * 16 + lr;
        float v = acc[m][n][r] + bias[col];
        posts_t[(size_t)(m0 + lrow) * 128 + col] = v;
        ps[lrow][col] = v;
      }
    }
  }
  __syncthreads();
  // z = mean + (2*sigmoid(sraw)+0.1)*noise for 64 rows x 64 cols
#pragma unroll
  for (int q = 0; q < 8; ++q) {
    int e = tid * 8 + q;  // 4096 work items
    int row = e >> 6, j = e & 63;
    float mean = ps[row][j];
    float sraw = ps[row][64 + j];
    float sd = 2.f / (1.f + expf(-sraw)) + 0.1f;
    float z = mean + sd * noise_t[(m0 + row) * 64 + j];
    zout[(m0 + row) * 64 + j] = z;
    feat[(size_t)(t * 256 + m0 + row) * 2112 + 2048 + j] = z;
  }
}

extern "C" void kernel_launch(void* const* d_in, const int* in_sizes, int n_in,
                              void* d_out, int out_size, void* d_ws,
                              size_t ws_size, hipStream_t stream) {
  const float* embeds = (const float*)d_in[0];
  const float* actions = (const float*)d_in[1];
  const float* h_t = (const float*)d_in[2];
  const float* z_t = (const float*)d_in[3];
  const float* noise = (const float*)d_in[4];
  const float* z_mlp_w = (const float*)d_in[5];
  const float* z_mlp_b = (const float*)d_in[6];
  const float* a_mlp_w = (const float*)d_in[7];
  const float* ln_za_s = (const float*)d_in[8];
  const float* ln_za_b = (const float*)d_in[9];
  const float* gru_wih = (const float*)d_in[10];
  const float* gru_whh = (const float*)d_in[11];
  const float* gru_bih = (const float*)d_in[12];
  const float* gru_bhh = (const float*)d_in[13];
  const float* post_h_w = (const float*)d_in[14];
  const float* post_h_b = (const float*)d_in[15];
  const float* post_e_w = (const float*)d_in[16];
  const float* post_e_b = (const float*)d_in[17];
  const float* ln_post_s = (const float*)d_in[18];
  const float* ln_post_b = (const float*)d_in[19];
  const float* post_w = (const float*)d_in[20];
  const float* post_b = (const float*)d_in[21];
  const float* prior_h_w = (const float*)d_in[22];
  const float* prior_h_b = (const float*)d_in[23];
  const float* ln_prior_s = (const float*)d_in[24];
  const float* ln_prior_b = (const float*)d_in[25];
  const float* prior_w = (const float*)d_in[26];
  const float* prior_b = (const float*)d_in[27];

  float* out = (float*)d_out;
  float* out_priors = out;           // [64,256,128]
  float* out_posts = out + 2097152;  // [64,256,128]
  float* out_z = out + 4194304;      // [64,256,64]
  float* out_feat = out + 5242880;   // [64,256,2112]

  char* ws = (char*)d_ws;
  size_t off = 0;
  auto alloc = [&](size_t bytes) {
    char* p = ws + off;
    off += (bytes + 255) & ~(size_t)255;
    return p;
  };
  // region W: Wpack during scan; prx_b during prior phase
  char* regW = alloc((size_t)8192 * 3072 * 2);  // 50.3 MB
  u16* wpack = (u16*)regW;
  u16* prx_b = (u16*)regW;
  u16* posth_b = (u16*)alloc((size_t)1024 * 2048 * 2);
  u16* priorh_b = (u16*)alloc((size_t)1024 * 2048 * 2);
  u16* postw_b = (u16*)alloc((size_t)128 * 1024 * 2);
  u16* priorw_b = (u16*)alloc((size_t)128 * 1024 * 2);
  u16* poste_b = (u16*)alloc((size_t)1024 * 1536 * 2);
  u16* acat = (u16*)alloc((size_t)256 * 3072 * 2);
  float* hf = (float*)alloc((size_t)256 * 2048 * 4);
  float* xbuf = (float*)alloc((size_t)256 * 1024 * 4);
  u16* p_b = (u16*)alloc((size_t)256 * 1024 * 2);
  // region U: e_part (33.55MB) + gout (8.4MB) during scan; p_pr after
  char* regU = alloc((size_t)42 * 1024 * 1024);
  u16* e_part = (u16*)regU;
  float* gout = (float*)(regU + 33554432);
  u16* p_pr = (u16*)regU;

  // ---- weight conversions + packing + h init (once per call) ----
  k_pack<<<24576, 256, 0, stream>>>(gru_wih, gru_whh, wpack);
  k_cvt<<<512, 256, 0, stream>>>(post_h_w, posth_b, 1024 * 2048);
  k_cvt<<<512, 256, 0, stream>>>(prior_h_w, priorh_b, 1024 * 2048);
  k_cvt<<<64, 256, 0, stream>>>(post_w, postw_b, 128 * 1024);
  k_cvt<<<64, 256, 0, stream>>>(prior_w, priorw_b, 128 * 1024);
  k_cvt<<<512, 256, 0, stream>>>(post_e_w, poste_b, 1024 * 1536);
  k_hinit<<<2048, 256, 0, stream>>>(h_t, hf, acat);

  // ---- batched embed projection: e_part = embeds@post_e_w^T + post_e_b ----
  k_gemm8<true, true, false><<<dim3(256, 8), 512, 0, stream>>>(
      embeds, 1536, poste_b, 1536, 0, 24, nullptr, e_part, 1024, post_e_b,
      nullptr);

  // ---- sequential scan ----
  for (int t = 0; t < 64; ++t) {
    const float* zsrc = (t == 0) ? z_t : (out_z + (size_t)(t - 1) * 16384);
    k_za<<<256, 256, 0, stream>>>(zsrc, actions + (size_t)t * 2560, z_mlp_w,
                                  z_mlp_b, a_mlp_w, ln_za_s, ln_za_b, acat);
    k_gemm8<false, false, true><<<256, 512, 0, stream>>>(
        acat, 3072, wpack, 3072, 0, 48, gout, nullptr, 8192, nullptr, nullptr);
    k_gate<<<2048, 256, 0, stream>>>(gout, gru_bih, gru_bhh, hf, acat,
                                     out_feat, t);
    k_gemm8<false, false, false><<<dim3(4, 8), 512, 0, stream>>>(
        acat + 1024, 3072, posth_b, 2048, 0, 32, xbuf, nullptr, 1024, post_h_b,
        e_part + (size_t)t * 262144);
    k_lnelu<false><<<256, 256, 0, stream>>>(xbuf, ln_post_s, ln_post_b, p_b);
    k_postz<<<4, 512, 0, stream>>>(p_b, postw_b, post_b,
                                   out_posts + (size_t)t * 32768,
                                   noise + (size_t)t * 16384,
                                   out_z + (size_t)t * 16384, out_feat, t);
  }

  // ---- batched prior head (Wpack dead; reuse regions) ----
  k_gemm8<true, true, false><<<dim3(256, 8), 512, 0, stream>>>(
      out_feat, 2112, priorh_b, 2048, 0, 32, nullptr, prx_b, 1024, prior_h_b,
      nullptr);
  k_lnelu<true><<<16384, 256, 0, stream>>>(prx_b, ln_prior_s, ln_prior_b, p_pr);
  k_gemm8<false, false, false><<<dim3(256, 1), 512, 0, stream>>>(
      p_pr, 1024, priorw_b, 1024, 0, 16, out_priors, nullptr, 128, prior_b,
      nullptr);
}

// Round 3
// 7119.016 us; speedup vs baseline: 2.3576x; 1.1991x over previous
//
#include <hip/hip_runtime.h>

#define LN_EPS 1e-3f

typedef short s8v __attribute__((ext_vector_type(8)));
typedef float f4v __attribute__((ext_vector_type(4)));
typedef unsigned short u16;

__device__ __forceinline__ u16 f2bf(float f) {
  unsigned int x = __float_as_uint(f);
  x += 0x7fffu + ((x >> 16) & 1u);
  return (u16)(x >> 16);
}
__device__ __forceinline__ float bf2f(u16 u) {
  return __uint_as_float(((unsigned int)u) << 16);
}

// async global->LDS, 16B per lane, wave-uniform LDS base
__device__ __forceinline__ void glds16(const u16* g, void* l) {
  __builtin_amdgcn_global_load_lds(
      (const __attribute__((address_space(1))) void*)g,
      (__attribute__((address_space(3))) void*)l, 16, 0, 0);
}

// ---------------- fp32 -> bf16 conversion ----------------
__global__ void k_cvt(const float* __restrict__ src, u16* __restrict__ dst, int n) {
  int i = blockIdx.x * blockDim.x + threadIdx.x;
  int stride = gridDim.x * blockDim.x;
  for (; i < n; i += stride) dst[i] = f2bf(src[i]);
}

// pack GRU weights, stage-linear chunk layout:
// wt[nt(32)][s(48)][sub(3)][ch(8)][row(64)][8]
// sub0 = r-gate [wih_r|whh_r], sub1 = u-gate, sub2 = s<16 ? ic(wih) : hc(whh)
__global__ void k_packgru(const float* __restrict__ wih,
                          const float* __restrict__ whh, u16* __restrict__ wt) {
  int u = blockIdx.x * 256 + threadIdx.x;  // 16B unit, total 2359296
  int nt = u / 73728;                      // 48*3*8*64
  int r1 = u % 73728;
  int s = r1 / 1536;
  int r2 = r1 % 1536;
  int sub = r2 / 512;
  int r3 = r2 % 512;
  int ch = r3 / 64;
  int row = r3 % 64;
  int j = nt * 64 + row;
  int kbase = s * 64 + ch * 8;
  s8v v;
#pragma unroll
  for (int e = 0; e < 8; ++e) {
    int kk = kbase + e;
    float x;
    if (sub == 0) {
      x = kk < 1024 ? wih[(size_t)j * 1024 + kk] : whh[(size_t)j * 2048 + kk - 1024];
    } else if (sub == 1) {
      int jj = 2048 + j;
      x = kk < 1024 ? wih[(size_t)jj * 1024 + kk] : whh[(size_t)jj * 2048 + kk - 1024];
    } else {
      int jj = 4096 + j;
      x = (s < 16) ? wih[(size_t)jj * 1024 + kk] : whh[(size_t)jj * 2048 + kk - 1024];
    }
    v[e] = (short)f2bf(x);
  }
  *(s8v*)(wt + (size_t)u * 8) = v;
}

// generic chunk-linear pack: dst[nt][s][ch(8)][row(BN)][8] from src[N][K] f32
__global__ void k_packB(const float* __restrict__ src, u16* __restrict__ dst,
                        int K, int BN, int total) {
  int u = blockIdx.x * 256 + threadIdx.x;
  if (u >= total) return;
  int ns = K >> 6;
  int perNt = ns * 8 * BN;
  int nt = u / perNt;
  int r1 = u % perNt;
  int s = r1 / (8 * BN);
  int r2 = r1 % (8 * BN);
  int ch = r2 / BN;
  int row = r2 % BN;
  int j = nt * BN + row;
  int k = s * 64 + ch * 8;
  const float* sp = src + (size_t)j * K + k;
  s8v v;
#pragma unroll
  for (int e = 0; e < 8; ++e) v[e] = (short)f2bf(sp[e]);
  *(s8v*)(dst + (size_t)u * 8) = v;
}

// h0 -> hf0 (f32) and acat0 h-slot (bf16)
__global__ void k_hinit(const float* __restrict__ h0, float* __restrict__ hf,
                        u16* __restrict__ acat) {
  int i = blockIdx.x * 256 + threadIdx.x;  // 524288
  int b = i >> 11, j = i & 2047;
  float v = h0[i];
  hf[i] = v;
  acat[(size_t)b * 3072 + 1024 + j] = f2bf(v);
}

// ---------------- za = elu(LN(concat(z@zw^T+zb, a@aw^T))) -> acat[:,0:1024] --
__global__ __launch_bounds__(256) void k_za(
    const float* __restrict__ zsrc, const float* __restrict__ act,
    const float* __restrict__ zw, const float* __restrict__ zb,
    const float* __restrict__ aw, const float* __restrict__ lns,
    const float* __restrict__ lnb, u16* __restrict__ acat) {
  const int b = blockIdx.x, tid = threadIdx.x;
  __shared__ float zsh[64];
  __shared__ float ash[12];
  __shared__ float wred[8];
  if (tid < 64) zsh[tid] = zsrc[b * 64 + tid];
  if (tid < 10) ash[tid] = act[b * 10 + tid];
  __syncthreads();
  float x[4];
#pragma unroll
  for (int i = 0; i < 2; ++i) {
    int c = tid + i * 256;
    const float4* wp = (const float4*)(zw + c * 64);
    float a = zb[c];
#pragma unroll
    for (int k = 0; k < 16; ++k) {
      float4 v = wp[k];
      a += zsh[k * 4] * v.x + zsh[k * 4 + 1] * v.y + zsh[k * 4 + 2] * v.z +
           zsh[k * 4 + 3] * v.w;
    }
    x[i] = a;
  }
#pragma unroll
  for (int i = 2; i < 4; ++i) {
    int c2 = tid + (i - 2) * 256;
    const float* wp = aw + c2 * 10;
    float a = 0.f;
#pragma unroll
    for (int k = 0; k < 10; ++k) a += ash[k] * wp[k];
    x[i] = a;
  }
  float s = x[0] + x[1] + x[2] + x[3];
#pragma unroll
  for (int o = 1; o < 64; o <<= 1) s += __shfl_xor(s, o);
  if ((tid & 63) == 0) wred[tid >> 6] = s;
  __syncthreads();
  float mu = (wred[0] + wred[1] + wred[2] + wred[3]) * (1.f / 1024.f);
  float q = 0.f;
#pragma unroll
  for (int i = 0; i < 4; ++i) {
    float d = x[i] - mu;
    q += d * d;
  }
#pragma unroll
  for (int o = 1; o < 64; o <<= 1) q += __shfl_xor(q, o);
  if ((tid & 63) == 0) wred[4 + (tid >> 6)] = q;
  __syncthreads();
  float rs = rsqrtf((wred[4] + wred[5] + wred[6] + wred[7]) * (1.f / 1024.f) + LN_EPS);
  int cols[4] = {tid, tid + 256, 512 + tid, 768 + tid};
#pragma unroll
  for (int i = 0; i < 4; ++i) {
    int c = cols[i];
    float y = (x[i] - mu) * rs * lns[c] + lnb[c];
    y = y > 0.f ? y : expm1f(y);
    acat[(size_t)b * 3072 + c] = f2bf(y);
  }
}

// ---------------- fused GRU: 3-gate GEMM + gate math + h update ----------
// BM=32, BN=64, BK=64, 48 fused stages, 2 LDS bufs, glds prefetch.
__global__ __launch_bounds__(256) void k_gru(
    const u16* __restrict__ acat_r, const u16* __restrict__ wt,
    const float* __restrict__ bih, const float* __restrict__ bhh,
    const float* __restrict__ hf_r, float* __restrict__ hf_w,
    u16* __restrict__ acat_w, float* __restrict__ feat, int t) {
  const int hw = blockIdx.x;
  const int logical = (hw & 7) * 32 + (hw >> 3);  // XCD-chunked
  const int mg = logical & 7;
  const int nt = logical >> 3;
  const int m0 = mg * 32;
  const int tid = threadIdx.x;
  const int lane = tid & 63;
  const int w = tid >> 6;  // 0..3
  const int lr = lane & 15, lk = lane >> 4;

  __shared__ __align__(16) char smem[2][28672];  // A 4KB + B 3x8KB per buf

  const int arow = 8 * w + (lane >> 3);
  const int acol8 = ((lane & 7) ^ (arow & 7)) * 8;  // pre-swizzled source
  const u16* aSrc = acat_r + (size_t)(m0 + arow) * 3072 + acol8;
  const u16* wtNt = wt + (size_t)nt * 48 * 3 * 4096;

  f4v accr[2], accu[2], acci[2], acch[2];
  accr[0] = accr[1] = accu[0] = accu[1] = (f4v)(0.f);
  acci[0] = acci[1] = acch[0] = acch[1] = (f4v)(0.f);

#define K1_STAGE(BB, S) { \
    char* base = &smem[BB][0]; \
    glds16(aSrc + (S) * 64, base + w * 1024); \
    const u16* bsrc = wtNt + (size_t)(S) * 3 * 4096; \
    _Pragma("unroll") for (int i = 0; i < 6; ++i) { \
      int cf = w + i * 4; \
      glds16(bsrc + (cf * 64 + lane) * 8, base + 4096 + cf * 1024); \
    } }

#define K1_COMP(BB, ACCX) { \
    char* base = &smem[BB][0]; \
    _Pragma("unroll") for (int kk = 0; kk < 2; ++kk) { \
      int ch = kk * 4 + lk; \
      int r0 = lr, r1 = 16 + lr; \
      s8v a0 = *(const s8v*)(base + r0 * 128 + ((ch ^ (r0 & 7)) * 16)); \
      s8v a1 = *(const s8v*)(base + r1 * 128 + ((ch ^ (r1 & 7)) * 16)); \
      int rb = (w * 16 + lr) * 16; \
      s8v br = *(const s8v*)(base + 4096 + ch * 1024 + rb); \
      s8v bu = *(const s8v*)(base + 12288 + ch * 1024 + rb); \
      s8v bx = *(const s8v*)(base + 20480 + ch * 1024 + rb); \
      accr[0] = __builtin_amdgcn_mfma_f32_16x16x32_bf16(a0, br, accr[0], 0, 0, 0); \
      accr[1] = __builtin_amdgcn_mfma_f32_16x16x32_bf16(a1, br, accr[1], 0, 0, 0); \
      accu[0] = __builtin_amdgcn_mfma_f32_16x16x32_bf16(a0, bu, accu[0], 0, 0, 0); \
      accu[1] = __builtin_amdgcn_mfma_f32_16x16x32_bf16(a1, bu, accu[1], 0, 0, 0); \
      ACCX[0] = __builtin_amdgcn_mfma_f32_16x16x32_bf16(a0, bx, ACCX[0], 0, 0, 0); \
      ACCX[1] = __builtin_amdgcn_mfma_f32_16x16x32_bf16(a1, bx, ACCX[1], 0, 0, 0); \
    } }

  K1_STAGE(0, 0)
  int buf = 0;
  for (int s = 0; s < 16; ++s) {
    asm volatile("s_waitcnt vmcnt(0)" ::: "memory");
    __builtin_amdgcn_s_barrier();
    __builtin_amdgcn_sched_barrier(0);
    K1_STAGE(buf ^ 1, s + 1)
    K1_COMP(buf, acci)
    buf ^= 1;
  }
  for (int s = 16; s < 48; ++s) {
    asm volatile("s_waitcnt vmcnt(0)" ::: "memory");
    __builtin_amdgcn_s_barrier();
    __builtin_amdgcn_sched_barrier(0);
    if (s + 1 < 48) K1_STAGE(buf ^ 1, s + 1)
    K1_COMP(buf, acch)
    buf ^= 1;
  }

  // epilogue: gate math. C/D layout: col=lane&15, row=(lane>>4)*4+reg
  const int j = nt * 64 + w * 16 + lr;
  const float b_ri = bih[j], b_rh = bhh[j];
  const float b_ui = bih[2048 + j], b_uh = bhh[2048 + j];
  const float b_ci = bih[4096 + j], b_ch = bhh[4096 + j];
#pragma unroll
  for (int m = 0; m < 2; ++m) {
#pragma unroll
    for (int r = 0; r < 4; ++r) {
      int grow = m0 + m * 16 + lk * 4 + r;
      float vr = accr[m][r] + b_ri + b_rh;
      float vu = accu[m][r] + b_ui + b_uh;
      float ic = acci[m][r] + b_ci;
      float hc = acch[m][r] + b_ch;
      float rg = 1.f / (1.f + expf(-vr));
      float ug = 1.f / (1.f + expf(-vu));
      float c = tanhf(ic + rg * hc);
      float hold = hf_r[(size_t)grow * 2048 + j];
      float h1 = (1.f - ug) * c + ug * hold;
      hf_w[(size_t)grow * 2048 + j] = h1;
      acat_w[(size_t)grow * 3072 + 1024 + j] = f2bf(h1);
      feat[(size_t)(t * 256 + grow) * 2112 + j] = h1;
    }
  }
#undef K1_STAGE
#undef K1_COMP
}

// ---------------- posterior hidden GEMM: x = h1@posthW^T + b + e_part ------
// BM=32, BN=64, 32 stages, same pipeline.
__global__ __launch_bounds__(256) void k_post(
    const u16* __restrict__ acat_h, const u16* __restrict__ wp,
    const float* __restrict__ bias, const u16* __restrict__ epart_t,
    float* __restrict__ xbuf) {
  const int bx = blockIdx.x;  // 128
  const int mg = bx & 7, nt = bx >> 3;
  const int m0 = mg * 32;
  const int tid = threadIdx.x;
  const int lane = tid & 63;
  const int w = tid >> 6;
  const int lr = lane & 15, lk = lane >> 4;

  __shared__ __align__(16) char smem[2][12288];  // A 4KB + B 8KB

  const int arow = 8 * w + (lane >> 3);
  const int acol8 = ((lane & 7) ^ (arow & 7)) * 8;
  const u16* aSrc = acat_h + (size_t)(m0 + arow) * 3072 + 1024 + acol8;
  const u16* wpNt = wp + (size_t)nt * 32 * 4096;

  f4v acc[2];
  acc[0] = (f4v)(0.f);
  acc[1] = (f4v)(0.f);

#define K2_STAGE(BB, S) { \
    char* base = &smem[BB][0]; \
    glds16(aSrc + (S) * 64, base + w * 1024); \
    const u16* bsrc = wpNt + (size_t)(S) * 4096; \
    _Pragma("unroll") for (int i = 0; i < 2; ++i) { \
      int cf = w + i * 4; \
      glds16(bsrc + (cf * 64 + lane) * 8, base + 4096 + cf * 1024); \
    } }

  K2_STAGE(0, 0)
  int buf = 0;
  for (int s = 0; s < 32; ++s) {
    asm volatile("s_waitcnt vmcnt(0)" ::: "memory");
    __builtin_amdgcn_s_barrier();
    __builtin_amdgcn_sched_barrier(0);
    if (s + 1 < 32) K2_STAGE(buf ^ 1, s + 1)
    char* base = &smem[buf][0];
#pragma unroll
    for (int kk = 0; kk < 2; ++kk) {
      int ch = kk * 4 + lk;
      int r0 = lr, r1 = 16 + lr;
      s8v a0 = *(const s8v*)(base + r0 * 128 + ((ch ^ (r0 & 7)) * 16));
      s8v a1 = *(const s8v*)(base + r1 * 128 + ((ch ^ (r1 & 7)) * 16));
      s8v b = *(const s8v*)(base + 4096 + ch * 1024 + (w * 16 + lr) * 16);
      acc[0] = __builtin_amdgcn_mfma_f32_16x16x32_bf16(a0, b, acc[0], 0, 0, 0);
      acc[1] = __builtin_amdgcn_mfma_f32_16x16x32_bf16(a1, b, acc[1], 0, 0, 0);
    }
    buf ^= 1;
  }
  const int col = nt * 64 + w * 16 + lr;
#pragma unroll
  for (int m = 0; m < 2; ++m) {
#pragma unroll
    for (int r = 0; r < 4; ++r) {
      int grow = m0 + m * 16 + lk * 4 + r;
      float v = acc[m][r] + bias[col] + bf2f(epart_t[(size_t)grow * 1024 + col]);
      xbuf[(size_t)grow * 1024 + col] = v;
    }
  }
#undef K2_STAGE
}

// ------------- posterior head: LN+ELU (fused in A-stage) + GEMM + z-sample --
// BM=32, N=128 (full), K=1024, 16 stages, 512 thr / 8 waves.
__global__ __launch_bounds__(512) void k_postz(
    const float* __restrict__ xb, const u16* __restrict__ pw,
    const float* __restrict__ lns, const float* __restrict__ lnb,
    const float* __restrict__ pb, float* __restrict__ posts_t,
    const float* __restrict__ noise_t, float* __restrict__ zout,
    float* __restrict__ feat, int t) {
  const int m0 = blockIdx.x * 32;
  const int tid = threadIdx.x;
  const int lane = tid & 63;
  const int w = tid >> 6;  // 0..7
  const int lr = lane & 15, lk = lane >> 4;
  __shared__ __align__(16) u16 As[2][32][64];
  __shared__ __align__(16) u16 Bs[2][8][128][8];
  __shared__ float lmu[32], lrs[32];
  __shared__ float ps[32][132];
  {
    int row = tid >> 4, sg = tid & 15;
    const float4* xp = (const float4*)(xb + (size_t)(m0 + row) * 1024 + sg * 64);
    float s = 0.f, q = 0.f;
#pragma unroll
    for (int i = 0; i < 16; ++i) {
      float4 v = xp[i];
      s += v.x + v.y + v.z + v.w;
      q += v.x * v.x + v.y * v.y + v.z * v.z + v.w * v.w;
    }
#pragma unroll
    for (int o = 1; o < 16; o <<= 1) {
      s += __shfl_xor(s, o);
      q += __shfl_xor(q, o);
    }
    if (sg == 0) {
      float mu = s * (1.f / 1024.f);
      lmu[row] = mu;
      lrs[row] = rsqrtf(q * (1.f / 1024.f) - mu * mu + LN_EPS);
    }
  }
  __syncthreads();

#define K3_STAGEA(BB, S) if (tid < 256) { \
    int row = tid >> 3, k8 = tid & 7; \
    const float* xp = xb + (size_t)(m0 + row) * 1024 + (S) * 64 + k8 * 8; \
    float mu = lmu[row], rs = lrs[row]; \
    s8v v; \
    _Pragma("unroll") for (int e = 0; e < 8; ++e) { \
      int c = (S) * 64 + k8 * 8 + e; \
      float y = (xp[e] - mu) * rs * lns[c] + lnb[c]; \
      y = y > 0.f ? y : expm1f(y); \
      v[e] = (short)f2bf(y); \
    } \
    *(s8v*)((char*)&As[BB][0][0] + row * 128 + ((k8 ^ (row & 7)) * 16)) = v; }

#define K3_STAGEB(BB, S) { \
    const u16* bsrc = pw + (size_t)(S) * 8192; \
    glds16(bsrc + (((w >> 1) * 128 + (w & 1) * 64 + lane) * 8), \
           (char*)&Bs[BB][0][0][0] + w * 1024); \
    glds16(bsrc + ((((w >> 1) + 4) * 128 + (w & 1) * 64 + lane) * 8), \
           (char*)&Bs[BB][0][0][0] + w * 1024 + 8192); }

  f4v acc[2];
  acc[0] = (f4v)(0.f);
  acc[1] = (f4v)(0.f);
  K3_STAGEA(0, 0)
  K3_STAGEB(0, 0)
  __syncthreads();
  int buf = 0;
  for (int s = 0; s < 16; ++s) {
    if (s + 1 < 16) {
      K3_STAGEA(buf ^ 1, s + 1)
      K3_STAGEB(buf ^ 1, s + 1)
    }
#pragma unroll
    for (int kk = 0; kk < 2; ++kk) {
      int ch = kk * 4 + lk;
      int r0 = lr, r1 = 16 + lr;
      s8v a0 = *(const s8v*)((char*)&As[buf][0][0] + r0 * 128 + ((ch ^ (r0 & 7)) * 16));
      s8v a1 = *(const s8v*)((char*)&As[buf][0][0] + r1 * 128 + ((ch ^ (r1 & 7)) * 16));
      s8v b = *(const s8v*)((char*)&Bs[buf][0][0][0] + ch * 2048 + (w * 16 + lr) * 16);
      acc[0] = __builtin_amdgcn_mfma_f32_16x16x32_bf16(a0, b, acc[0], 0, 0, 0);
      acc[1] = __builtin_amdgcn_mfma_f32_16x16x32_bf16(a1, b, acc[1], 0, 0, 0);
    }
    __syncthreads();
    buf ^= 1;
  }
#pragma unroll
  for (int m = 0; m < 2; ++m) {
#pragma unroll
    for (int r = 0; r < 4; ++r) {
      int row = m * 16 + lk * 4 + r;
      int col = w * 16 + lr;
      float v = acc[m][r] + pb[col];
      posts_t[(size_t)(m0 + row) * 128 + col] = v;
      ps[row][col] = v;
    }
  }
  __syncthreads();
#pragma unroll
  for (int q = 0; q < 4; ++q) {
    int e = q * 512 + tid;
    int row = e >> 6, j = e & 63;
    float mean = ps[row][j], sraw = ps[row][64 + j];
    float sd = 2.f / (1.f + expf(-sraw)) + 0.1f;
    float z = mean + sd * noise_t[(m0 + row) * 64 + j];
    zout[(m0 + row) * 64 + j] = z;
    feat[(size_t)(t * 256 + m0 + row) * 2112 + 2048 + j] = z;
  }
#undef K3_STAGEA
#undef K3_STAGEB
}

// ---------------- batched 8-wave GEMM (embed / prior phases) ----------------
// C[M,N] = A[M,K] @ Bw[N,K]^T (+bias). BM=64, BN=128, 512 thr.
template <bool AF32, bool OUTBF16>
__global__ __launch_bounds__(512) void k_gemm8(
    const void* __restrict__ Av, int lda, const u16* __restrict__ Bw, int ldb,
    int nstage, float* __restrict__ Cf, u16* __restrict__ Cb, int ldc,
    const float* __restrict__ bias) {
  const int bx = blockIdx.x, by = blockIdx.y;
  const int tid = threadIdx.x;
  const int m0 = bx * 64;
  const int n0 = by * 128;
  __shared__ __align__(16) u16 As[64][72];
  __shared__ __align__(16) u16 Bs[128][72];
  const int lane = tid & 63;
  const int w = tid >> 6;
  const int wr = w >> 2;
  const int wc = w & 3;
  const int lr = lane & 15;
  const int lk = lane >> 4;

  f4v acc[2][2];
#pragma unroll
  for (int m = 0; m < 2; ++m)
#pragma unroll
    for (int n = 0; n < 2; ++n) acc[m][n] = (f4v)(0.0f);

  for (int s = 0; s < nstage; ++s) {
    const int k0 = s << 6;
    {
      int row = tid >> 3, k8 = (tid & 7) << 3;
      if (AF32) {
        const float* ap = (const float*)Av + (size_t)(m0 + row) * lda + k0 + k8;
        float4 f0 = *(const float4*)ap;
        float4 f1 = *(const float4*)(ap + 4);
        s8v v;
        v[0] = (short)f2bf(f0.x); v[1] = (short)f2bf(f0.y);
        v[2] = (short)f2bf(f0.z); v[3] = (short)f2bf(f0.w);
        v[4] = (short)f2bf(f1.x); v[5] = (short)f2bf(f1.y);
        v[6] = (short)f2bf(f1.z); v[7] = (short)f2bf(f1.w);
        *(s8v*)&As[row][k8] = v;
      } else {
        *(s8v*)&As[row][k8] =
            *(const s8v*)((const u16*)Av + (size_t)(m0 + row) * lda + k0 + k8);
      }
    }
#pragma unroll
    for (int it = 0; it < 2; ++it) {
      int c = tid + it * 512;
      int row = c >> 3, k8 = (c & 7) << 3;
      *(s8v*)&Bs[row][k8] = *(const s8v*)(Bw + (size_t)(n0 + row) * ldb + k0 + k8);
    }
    __syncthreads();
#pragma unroll
    for (int kk = 0; kk < 2; ++kk) {
      const int koff = kk * 32 + lk * 8;
      s8v a[2], b[2];
      a[0] = *(const s8v*)&As[wr * 32 + lr][koff];
      a[1] = *(const s8v*)&As[wr * 32 + 16 + lr][koff];
      b[0] = *(const s8v*)&Bs[wc * 32 + lr][koff];
      b[1] = *(const s8v*)&Bs[wc * 32 + 16 + lr][koff];
#pragma unroll
      for (int m = 0; m < 2; ++m)
#pragma unroll
        for (int n = 0; n < 2; ++n)
          acc[m][n] =
              __builtin_amdgcn_mfma_f32_16x16x32_bf16(a[m], b[n], acc[m][n], 0, 0, 0);
    }
    __syncthreads();
  }
#pragma unroll
  for (int m = 0; m < 2; ++m) {
#pragma unroll
    for (int n = 0; n < 2; ++n) {
#pragma unroll
      for (int r = 0; r < 4; ++r) {
        int row = m0 + wr * 32 + m * 16 + lk * 4 + r;
        int col = n0 + wc * 32 + n * 16 + lr;
        float v = acc[m][n][r];
        if (bias) v += bias[col];
        if (OUTBF16)
          Cb[(size_t)row * ldc + col] = f2bf(v);
        else
          Cf[(size_t)row * ldc + col] = v;
      }
    }
  }
}

// ---------------- LN + ELU (rows of 1024), bf16 in/out ----------------
__global__ __launch_bounds__(256) void k_lnelu(const u16* __restrict__ xsrc,
                                               const float* __restrict__ s,
                                               const float* __restrict__ bb,
                                               u16* __restrict__ out) {
  int row = blockIdx.x, tid = threadIdx.x;
  __shared__ float red[256];
  float v[4];
#pragma unroll
  for (int i = 0; i < 4; ++i) {
    size_t idx = (size_t)row * 1024 + tid + i * 256;
    v[i] = bf2f(xsrc[idx]);
  }
  float sm = v[0] + v[1] + v[2] + v[3];
  red[tid] = sm;
  __syncthreads();
  for (int o = 128; o > 0; o >>= 1) {
    if (tid < o) red[tid] += red[tid + o];
    __syncthreads();
  }
  float mu = red[0] * (1.0f / 1024.0f);
  __syncthreads();
  float q = 0.f;
#pragma unroll
  for (int i = 0; i < 4; ++i) {
    float d = v[i] - mu;
    q += d * d;
  }
  red[tid] = q;
  __syncthreads();
  for (int o = 128; o > 0; o >>= 1) {
    if (tid < o) red[tid] += red[tid + o];
    __syncthreads();
  }
  float rs = rsqrtf(red[0] * (1.0f / 1024.0f) + LN_EPS);
#pragma unroll
  for (int i = 0; i < 4; ++i) {
    int c = tid + i * 256;
    float y = (v[i] - mu) * rs * s[c] + bb[c];
    y = y > 0.f ? y : expm1f(y);
    out[(size_t)row * 1024 + c] = f2bf(y);
  }
}

extern "C" void kernel_launch(void* const* d_in, const int* in_sizes, int n_in,
                              void* d_out, int out_size, void* d_ws,
                              size_t ws_size, hipStream_t stream) {
  const float* embeds = (const float*)d_in[0];
  const float* actions = (const float*)d_in[1];
  const float* h_t = (const float*)d_in[2];
  const float* z_t = (const float*)d_in[3];
  const float* noise = (const float*)d_in[4];
  const float* z_mlp_w = (const float*)d_in[5];
  const float* z_mlp_b = (const float*)d_in[6];
  const float* a_mlp_w = (const float*)d_in[7];
  const float* ln_za_s = (const float*)d_in[8];
  const float* ln_za_b = (const float*)d_in[9];
  const float* gru_wih = (const float*)d_in[10];
  const float* gru_whh = (const float*)d_in[11];
  const float* gru_bih = (const float*)d_in[12];
  const float* gru_bhh = (const float*)d_in[13];
  const float* post_h_w = (const float*)d_in[14];
  const float* post_h_b = (const float*)d_in[15];
  const float* post_e_w = (const float*)d_in[16];
  const float* post_e_b = (const float*)d_in[17];
  const float* ln_post_s = (const float*)d_in[18];
  const float* ln_post_b = (const float*)d_in[19];
  const float* post_w = (const float*)d_in[20];
  const float* post_b = (const float*)d_in[21];
  const float* prior_h_w = (const float*)d_in[22];
  const float* prior_h_b = (const float*)d_in[23];
  const float* ln_prior_s = (const float*)d_in[24];
  const float* ln_prior_b = (const float*)d_in[25];
  const float* prior_w = (const float*)d_in[26];
  const float* prior_b = (const float*)d_in[27];

  float* out = (float*)d_out;
  float* out_priors = out;           // [64,256,128]
  float* out_posts = out + 2097152;  // [64,256,128]
  float* out_z = out + 4194304;      // [64,256,64]
  float* out_feat = out + 5242880;   // [64,256,2112]

  char* ws = (char*)d_ws;
  size_t off = 0;
  auto alloc = [&](size_t bytes) {
    char* p = ws + off;
    off += (bytes + 255) & ~(size_t)255;
    return p;
  };
  // region W: GRU Wt pack during scan; prx_b during prior phase
  char* regW = alloc((size_t)32 * 48 * 3 * 4096 * 2);  // 37.75 MB
  u16* wt = (u16*)regW;
  u16* prx_b = (u16*)regW;
  u16* posthP = (u16*)alloc((size_t)1024 * 2048 * 2);
  u16* postwP = (u16*)alloc((size_t)128 * 1024 * 2);
  u16* poste_b = (u16*)alloc((size_t)1024 * 1536 * 2);
  u16* priorh_b = (u16*)alloc((size_t)1024 * 2048 * 2);
  u16* priorw_b = (u16*)alloc((size_t)128 * 1024 * 2);
  u16* acat0 = (u16*)alloc((size_t)256 * 3072 * 2);
  u16* acat1 = (u16*)alloc((size_t)256 * 3072 * 2);
  float* hf0 = (float*)alloc((size_t)256 * 2048 * 4);
  float* hf1 = (float*)alloc((size_t)256 * 2048 * 4);
  float* xbuf = (float*)alloc((size_t)256 * 1024 * 4);
  // region U: e_part during scan; p_pr during prior phase
  char* regU = alloc((size_t)16384 * 1024 * 2);  // 33.55 MB
  u16* e_part = (u16*)regU;
  u16* p_pr = (u16*)regU;

  u16* acat[2] = {acat0, acat1};
  float* hf[2] = {hf0, hf1};

  // ---- packing + conversions + h init ----
  k_packgru<<<9216, 256, 0, stream>>>(gru_wih, gru_whh, wt);
  k_packB<<<1024, 256, 0, stream>>>(post_h_w, posthP, 2048, 64, 262144);
  k_packB<<<64, 256, 0, stream>>>(post_w, postwP, 1024, 128, 16384);
  k_cvt<<<512, 256, 0, stream>>>(post_e_w, poste_b, 1024 * 1536);
  k_cvt<<<512, 256, 0, stream>>>(prior_h_w, priorh_b, 1024 * 2048);
  k_cvt<<<64, 256, 0, stream>>>(prior_w, priorw_b, 128 * 1024);
  k_hinit<<<2048, 256, 0, stream>>>(h_t, hf0, acat0);

  // ---- batched embed projection: e_part = embeds@post_e_w^T + post_e_b ----
  k_gemm8<true, true><<<dim3(256, 8), 512, 0, stream>>>(
      embeds, 1536, poste_b, 1536, 24, nullptr, e_part, 1024, post_e_b);

  // ---- sequential scan ----
  for (int t = 0; t < 64; ++t) {
    const int rI = t & 1, wI = rI ^ 1;
    const float* zsrc = (t == 0) ? z_t : (out_z + (size_t)(t - 1) * 16384);
    k_za<<<256, 256, 0, stream>>>(zsrc, actions + (size_t)t * 2560, z_mlp_w,
                                  z_mlp_b, a_mlp_w, ln_za_s, ln_za_b, acat[rI]);
    k_gru<<<256, 256, 0, stream>>>(acat[rI], wt, gru_bih, gru_bhh, hf[rI],
                                   hf[wI], acat[wI], out_feat, t);
    k_post<<<128, 256, 0, stream>>>(acat[wI], posthP, post_h_b,
                                    e_part + (size_t)t * 262144, xbuf);
    k_postz<<<8, 512, 0, stream>>>(xbuf, postwP, ln_post_s, ln_post_b, post_b,
                                   out_posts + (size_t)t * 32768,
                                   noise + (size_t)t * 16384,
                                   out_z + (size_t)t * 16384, out_feat, t);
  }

  // ---- batched prior head (wt/e_part dead; reuse regions) ----
  k_gemm8<true, true><<<dim3(256, 8), 512, 0, stream>>>(
      out_feat, 2112, priorh_b, 2048, 32, nullptr, prx_b, 1024, prior_h_b);
  k_lnelu<<<16384, 256, 0, stream>>>(prx_b, ln_prior_s, ln_prior_b, p_pr);
  k_gemm8<false, false><<<dim3(256, 1), 512, 0, stream>>>(
      p_pr, 1024, priorw_b, 1024, 16, out_priors, nullptr, 128, prior_b);
}